// Round 4
// baseline (63.818 us; speedup 1.0000x reference)
//
#include <hip/hip_runtime.h>

// ChamferDistance: B=4, N=M=8192, fp32 3-D points.
// R4: MFMA formulation. d[i][j] = n1_i + n2_j - 2 x_i.y_j is a K=13 bf16
// matmul with hi/lo error compensation:
//   A (x-side, K dims): [-2xh(3), -2xl(3), -2xh(3), n1h, n1l, 1, 1, 0..]
//   B (y-side, K dims): [  yh(3),   yh(3),   yl(3),  1,  1, n2h, n2l, 0..]
//   dot = -2(xh.yh + xl.yh + xh.yl) + n1 + n2   (drops xl.yl ~ 1e-5)
// One 16x16x32_bf16 MFMA per 256-el tile computes d exactly-enough; dist1 =
// running per-reg row-min (16 v_min / 1024 els), dist2 = per-lane min3-tree +
// 2 shuffles + LDS atomicMin. Both outputs from ONE d evaluation (work /2 vs
// two-direction scalar). Partials combine via int-punned atomicMin (valid:
// values clamped >= 0 before the atomic; clamp commutes with min).

typedef short short8 __attribute__((ext_vector_type(8)));
typedef float f32x4  __attribute__((ext_vector_type(4)));

#define B_      4
#define NPT     8192
#define THREADS 256
#define XB      32                  // x blocks per batch, 256 rows each
#define NCHUNK  8                   // y chunks per batch
#define CHUNK   (NPT / NCHUNK)      // 1024 cols per chunk
#define PINF_I  0x7f800000

__device__ __forceinline__ unsigned short f2bf(float x) {
    unsigned u = __float_as_uint(x);
    u += 0x7fff + ((u >> 16) & 1);          // RNE; inputs are small/finite
    return (unsigned short)(u >> 16);
}
__device__ __forceinline__ float bf2f(unsigned short b) {
    return __uint_as_float(((unsigned)b) << 16);
}
#define PK2(a, b) ((((unsigned)(b)) << 16) | (unsigned)(a))

__global__ __launch_bounds__(THREADS)
void cd_pack(const float* __restrict__ xyz1, const float* __restrict__ xyz2,
             unsigned short* __restrict__ pkA, unsigned short* __restrict__ pkB,
             int* __restrict__ out) {
    int i = blockIdx.x * THREADS + threadIdx.x;
    if (i >= B_ * NPT) return;
    const unsigned short one = 0x3f80;      // bf16(1.0)

    {   // cloud 1 -> A-side packing (16 ushorts per point)
        float x0 = xyz1[3*i], x1 = xyz1[3*i+1], x2 = xyz1[3*i+2];
        unsigned short h0 = f2bf(x0), h1 = f2bf(x1), h2 = f2bf(x2);
        unsigned short l0 = f2bf(x0 - bf2f(h0)), l1 = f2bf(x1 - bf2f(h1)), l2 = f2bf(x2 - bf2f(h2));
        unsigned short m0 = f2bf(-2.f * bf2f(h0)), m1 = f2bf(-2.f * bf2f(h1)), m2 = f2bf(-2.f * bf2f(h2));
        unsigned short q0 = f2bf(-2.f * bf2f(l0)), q1 = f2bf(-2.f * bf2f(l1)), q2 = f2bf(-2.f * bf2f(l2));
        float n = x0*x0 + x1*x1 + x2*x2;
        unsigned short nh = f2bf(n), nl = f2bf(n - bf2f(nh));
        uint4 w0 = make_uint4(PK2(m0, m1), PK2(m2, q0), PK2(q1, q2), PK2(m0, m1));
        uint4 w1 = make_uint4(PK2(m2, nh), PK2(nl, one), PK2(one, 0), PK2(0, 0));
        ((uint4*)pkA)[(size_t)i * 2]     = w0;
        ((uint4*)pkA)[(size_t)i * 2 + 1] = w1;
    }
    {   // cloud 2 -> B-side packing
        float y0 = xyz2[3*i], y1 = xyz2[3*i+1], y2 = xyz2[3*i+2];
        unsigned short h0 = f2bf(y0), h1 = f2bf(y1), h2 = f2bf(y2);
        unsigned short l0 = f2bf(y0 - bf2f(h0)), l1 = f2bf(y1 - bf2f(h1)), l2 = f2bf(y2 - bf2f(h2));
        float n = y0*y0 + y1*y1 + y2*y2;
        unsigned short nh = f2bf(n), nl = f2bf(n - bf2f(nh));
        uint4 w0 = make_uint4(PK2(h0, h1), PK2(h2, h0), PK2(h1, h2), PK2(l0, l1));
        uint4 w1 = make_uint4(PK2(l2, one), PK2(one, nh), PK2(nl, 0), PK2(0, 0));
        ((uint4*)pkB)[(size_t)i * 2]     = w0;
        ((uint4*)pkB)[(size_t)i * 2 + 1] = w1;
    }
    out[i] = PINF_I;                  // dist1 init
    out[(size_t)B_ * NPT + i] = PINF_I; // dist2 init
}

__global__ __launch_bounds__(THREADS)
void cd_mfma(const unsigned short* __restrict__ pkA,
             const unsigned short* __restrict__ pkB,
             int* __restrict__ out) {
    __shared__ int colmin[CHUNK];

    const int tid = threadIdx.x;
    int bid = blockIdx.x;
    const int c  = bid & (NCHUNK - 1);  bid >>= 3;
    const int xb = bid & (XB - 1);      bid >>= 5;
    const int b  = bid;

    for (int i = tid; i < CHUNK; i += THREADS) colmin[i] = PINF_I;
    __syncthreads();

    const int lane = tid & 63;
    const int w    = tid >> 6;        // wave 0..3
    const int l15  = lane & 15;
    const int kg   = lane >> 4;       // k-group 0..3 (only 0,1 load; 2,3 zero)

    const size_t bbase = (size_t)b * NPT;
    const int rowBase  = xb * 256 + w * 64;

    // A fragments: 4 row-tiles x 16 rows, held in regs for the whole sweep
    short8 afrag[4];
    #pragma unroll
    for (int rt = 0; rt < 4; ++rt) {
        short8 f = {};
        if (kg < 2)
            f = *(const short8*)(pkA + (bbase + rowBase + rt * 16 + l15) * 16 + kg * 8);
        afrag[rt] = f;
    }

    float rmin[4][4];
    #pragma unroll
    for (int rt = 0; rt < 4; ++rt)
        #pragma unroll
        for (int j = 0; j < 4; ++j) rmin[rt][j] = __int_as_float(PINF_I);

    const int ybase0 = c * CHUNK;

    for (int t = 0; t < CHUNK / 16; ++t) {          // 64 y-tiles of 16 cols
        short8 bfrag = {};
        if (kg < 2)
            bfrag = *(const short8*)(pkB + (bbase + ybase0 + t * 16 + l15) * 16 + kg * 8);

        f32x4 acc[4];
        #pragma unroll
        for (int rt = 0; rt < 4; ++rt) {
            f32x4 z = {0.f, 0.f, 0.f, 0.f};
            acc[rt] = __builtin_amdgcn_mfma_f32_16x16x32_bf16(afrag[rt], bfrag, z, 0, 0, 0);
        }
        // dist1: running row-min per accumulator register
        #pragma unroll
        for (int rt = 0; rt < 4; ++rt)
            #pragma unroll
            for (int j = 0; j < 4; ++j)
                rmin[rt][j] = fminf(rmin[rt][j], acc[rt][j]);
        // dist2: per-lane min over the wave's 64 rows for col = lane&15
        float c0 = fminf(fminf(acc[0][0], acc[0][1]), fminf(acc[0][2], acc[0][3]));
        float c1 = fminf(fminf(acc[1][0], acc[1][1]), fminf(acc[1][2], acc[1][3]));
        float c2 = fminf(fminf(acc[2][0], acc[2][1]), fminf(acc[2][2], acc[2][3]));
        float c3 = fminf(fminf(acc[3][0], acc[3][1]), fminf(acc[3][2], acc[3][3]));
        float cm = fminf(fminf(c0, c1), fminf(c2, c3));
        cm = fminf(cm, __shfl_xor(cm, 16, 64));     // combine kg pairs
        cm = fminf(cm, __shfl_xor(cm, 32, 64));
        if (lane < 16) atomicMin(&colmin[t * 16 + l15], __float_as_int(cm));
    }

    // dist1 epilogue: butterfly across the 16 cols, then one lane per kg writes
    const size_t gRow = bbase + (size_t)rowBase;
    #pragma unroll
    for (int rt = 0; rt < 4; ++rt) {
        #pragma unroll
        for (int j = 0; j < 4; ++j) {
            float v = rmin[rt][j];
            v = fminf(v, __shfl_xor(v, 1, 64));
            v = fminf(v, __shfl_xor(v, 2, 64));
            v = fminf(v, __shfl_xor(v, 4, 64));
            v = fminf(v, __shfl_xor(v, 8, 64));
            if (l15 == 0)
                atomicMin(&out[gRow + rt * 16 + kg * 4 + j],
                          __float_as_int(fmaxf(v, 0.f)));
        }
    }

    // dist2 epilogue: flush LDS col-mins
    __syncthreads();
    int* o2 = out + (size_t)B_ * NPT;
    const size_t gCol = bbase + ybase0;
    for (int i = tid; i < CHUNK; i += THREADS) {
        float v = fmaxf(__int_as_float(colmin[i]), 0.f);
        atomicMin(&o2[gCol + i], __float_as_int(v));
    }
}

extern "C" void kernel_launch(void* const* d_in, const int* in_sizes, int n_in,
                              void* d_out, int out_size, void* d_ws, size_t ws_size,
                              hipStream_t stream) {
    const float* xyz1 = (const float*)d_in[0];
    const float* xyz2 = (const float*)d_in[1];

    unsigned short* pkA = (unsigned short*)d_ws;             // B*NPT*32 B = 1 MB
    unsigned short* pkB = pkA + (size_t)B_ * NPT * 16;       // 1 MB

    cd_pack<<<(B_ * NPT + THREADS - 1) / THREADS, THREADS, 0, stream>>>(
        xyz1, xyz2, pkA, pkB, (int*)d_out);

    cd_mfma<<<B_ * XB * NCHUNK, THREADS, 0, stream>>>(pkA, pkB, (int*)d_out);
}

// Round 5
// 37.758 us; speedup vs baseline: 1.6902x; 1.6902x over previous
//
#include <hip/hip_runtime.h>

// ChamferDistance: B=4, N=M=8192, fp32 3-D points.
// R5: two-orientation MFMA. d = n1 + n2 - 2 x.y as a K=16 bf16 matmul
// (32x32x16: K matches packed point exactly, no zero-padding, no masks).
// Hi/lo error compensation (verified R4, absmax 0.0156):
//   A-form(p): [-2ph(3), -2pl(3), -2ph(3), nh, nl, 1, 1, 0,0,0]
//   B-form(p): [  ph(3),   ph(3),   pl(3),  1,  1, nh, nl, 0,0,0]
//   dot = -2(ph.qh + pl.qh + ph.ql) + np + nq   (drops pl.ql ~ 1e-5)
// Each pass computes d in the orientation where ITS output is the row-min:
// hot loop = 1 load + 2 MFMA + 32 running fmin per 2048 elements — no
// shuffles / LDS / atomics / exec-masking in the loop (R4's 62-µs sin).
// Cross-lane butterfly + global atomicMin (int-punned, non-neg) once per wave.

typedef short  short8 __attribute__((ext_vector_type(8)));
typedef float  f32x16 __attribute__((ext_vector_type(16)));

#define B_      4
#define NPT     8192
#define THREADS 256
#define ROWBLK  32              // 256-row blocks per (pass, batch)
#define NCHUNK  4               // col chunks  -> grid = 2*4*32*4 = 1024
#define CCOLS   (NPT / NCHUNK)  // 2048 cols per chunk
#define PINF_I  0x7f800000

__device__ __forceinline__ unsigned short f2bf(float x) {
    unsigned u = __float_as_uint(x);
    u += 0x7fff + ((u >> 16) & 1);          // RNE; inputs small/finite
    return (unsigned short)(u >> 16);
}
__device__ __forceinline__ float bf2f(unsigned short b) {
    return __uint_as_float(((unsigned)b) << 16);
}
#define PK2(a, b) ((((unsigned)(b)) << 16) | (unsigned)(a))

__device__ __forceinline__ void pack_point(const float* __restrict__ xyz, int i,
                                           unsigned short* __restrict__ Aform,
                                           unsigned short* __restrict__ Bform) {
    const unsigned short one = 0x3f80;
    float x0 = xyz[3*i], x1 = xyz[3*i+1], x2 = xyz[3*i+2];
    unsigned short h0 = f2bf(x0), h1 = f2bf(x1), h2 = f2bf(x2);
    unsigned short l0 = f2bf(x0 - bf2f(h0)), l1 = f2bf(x1 - bf2f(h1)), l2 = f2bf(x2 - bf2f(h2));
    unsigned short m0 = f2bf(-2.f * bf2f(h0)), m1 = f2bf(-2.f * bf2f(h1)), m2 = f2bf(-2.f * bf2f(h2));
    unsigned short q0 = f2bf(-2.f * bf2f(l0)), q1 = f2bf(-2.f * bf2f(l1)), q2 = f2bf(-2.f * bf2f(l2));
    float n = x0*x0 + x1*x1 + x2*x2;
    unsigned short nh = f2bf(n), nl = f2bf(n - bf2f(nh));
    uint4 a0 = make_uint4(PK2(m0, m1), PK2(m2, q0), PK2(q1, q2), PK2(m0, m1));
    uint4 a1 = make_uint4(PK2(m2, nh), PK2(nl, one), PK2(one, 0), PK2(0, 0));
    ((uint4*)Aform)[(size_t)i * 2]     = a0;
    ((uint4*)Aform)[(size_t)i * 2 + 1] = a1;
    uint4 b0 = make_uint4(PK2(h0, h1), PK2(h2, h0), PK2(h1, h2), PK2(l0, l1));
    uint4 b1 = make_uint4(PK2(l2, one), PK2(one, nh), PK2(nl, 0), PK2(0, 0));
    ((uint4*)Bform)[(size_t)i * 2]     = b0;
    ((uint4*)Bform)[(size_t)i * 2 + 1] = b1;
}

__global__ __launch_bounds__(THREADS)
void cd_pack(const float* __restrict__ xyz1, const float* __restrict__ xyz2,
             unsigned short* __restrict__ A1, unsigned short* __restrict__ B1,
             unsigned short* __restrict__ A2, unsigned short* __restrict__ B2,
             int* __restrict__ out) {
    int i = blockIdx.x * THREADS + threadIdx.x;
    if (i >= B_ * NPT) return;
    pack_point(xyz1, i, A1, B1);
    pack_point(xyz2, i, A2, B2);
    out[i] = PINF_I;                        // dist1 init
    out[(size_t)B_ * NPT + i] = PINF_I;     // dist2 init
}

__global__ __launch_bounds__(THREADS, 4)    // keep <=128 VGPR -> 4 waves/SIMD
void cd_mfma32(const unsigned short* __restrict__ A1, const unsigned short* __restrict__ B1,
               const unsigned short* __restrict__ A2, const unsigned short* __restrict__ B2,
               int* __restrict__ out) {
    int bid = blockIdx.x;
    const int c    = bid & (NCHUNK - 1);  bid >>= 2;
    const int rb   = bid & (ROWBLK - 1);  bid >>= 5;
    const int b    = bid & (B_ - 1);      bid >>= 2;
    const int pass = bid;                               // 0: dist1, 1: dist2

    const unsigned short* __restrict__ Ap = pass ? A2 : A1;
    const unsigned short* __restrict__ Bp = pass ? B1 : B2;
    int* __restrict__ o = out + (size_t)pass * B_ * NPT;

    const int tid  = threadIdx.x;
    const int lane = tid & 63;
    const int w    = tid >> 6;
    const int l31  = lane & 31;
    const int kg   = lane >> 5;            // k-half: k = kg*8 + i

    const size_t bbase   = (size_t)b * NPT;
    const int    rowBase = rb * 256 + w * 64;

    // A fragments: 2 row-tiles x 32 rows, resident for the whole sweep
    short8 afrag[2];
    #pragma unroll
    for (int rt = 0; rt < 2; ++rt)
        afrag[rt] = *(const short8*)(Ap + (bbase + rowBase + rt*32 + l31) * 16 + kg * 8);

    float rmin[2][16];
    #pragma unroll
    for (int rt = 0; rt < 2; ++rt)
        #pragma unroll
        for (int r = 0; r < 16; ++r) rmin[rt][r] = __int_as_float(PINF_I);

    // Hot loop: 1 dwordx4 load + 2 MFMA + 32 fmin per 32-col tile (2048 els)
    const short8* __restrict__ bptr =
        (const short8*)(Bp + (bbase + (size_t)c * CCOLS + l31) * 16 + kg * 8);
    for (int t = 0; t < CCOLS / 32; ++t) {
        short8 bfrag = bptr[(size_t)t * 64];     // 32 points * 16 ushorts / 8
        #pragma unroll
        for (int rt = 0; rt < 2; ++rt) {
            f32x16 z = {0.f};
            f32x16 acc = __builtin_amdgcn_mfma_f32_32x32x16_bf16(afrag[rt], bfrag, z, 0, 0, 0);
            #pragma unroll
            for (int r = 0; r < 16; ++r)
                rmin[rt][r] = fminf(rmin[rt][r], acc[r]);
        }
    }

    // Epilogue: butterfly each row-min across the 32 col-slots, one atomic/row
    #pragma unroll
    for (int rt = 0; rt < 2; ++rt) {
        #pragma unroll
        for (int r = 0; r < 16; ++r) {
            float v = rmin[rt][r];
            v = fminf(v, __shfl_xor(v, 1, 64));
            v = fminf(v, __shfl_xor(v, 2, 64));
            v = fminf(v, __shfl_xor(v, 4, 64));
            v = fminf(v, __shfl_xor(v, 8, 64));
            v = fminf(v, __shfl_xor(v, 16, 64));
            if (l31 == 0) {
                int row = rowBase + rt*32 + (r & 3) + 8*(r >> 2) + 4*kg;
                atomicMin(&o[bbase + row], __float_as_int(fmaxf(v, 0.f)));
            }
        }
    }
}

extern "C" void kernel_launch(void* const* d_in, const int* in_sizes, int n_in,
                              void* d_out, int out_size, void* d_ws, size_t ws_size,
                              hipStream_t stream) {
    const float* xyz1 = (const float*)d_in[0];
    const float* xyz2 = (const float*)d_in[1];

    const size_t PSZ = (size_t)B_ * NPT * 16;       // ushorts per packed array
    unsigned short* A1 = (unsigned short*)d_ws;     // 4 x 1 MB in d_ws
    unsigned short* B1 = A1 + PSZ;
    unsigned short* A2 = B1 + PSZ;
    unsigned short* B2 = A2 + PSZ;

    cd_pack<<<(B_ * NPT + THREADS - 1) / THREADS, THREADS, 0, stream>>>(
        xyz1, xyz2, A1, B1, A2, B2, (int*)d_out);

    cd_mfma32<<<2 * B_ * ROWBLK * NCHUNK, THREADS, 0, stream>>>(
        A1, B1, A2, B2, (int*)d_out);
}